// Round 10
// baseline (247.073 us; speedup 1.0000x reference)
//
#include <hip/hip_runtime.h>
#include <math.h>

// Problem constants (from reference)
#define NG   1024        // graphs
#define NP   256         // nodes per graph
#define EPG  4096        // edges per graph
#define ETOT 4194304     // total edges
#define FIN  7
#define HD   64
#define KC   50
#define FST  72          // f16 LDS row stride for 64-col tiles (36w = 4 mod 32)
#define TST  264         // t1T row stride halves (132w = 4 mod 32)
#define AST2 132         // T1T row stride halves (66w = 2 mod 32)
#define TSC  0.00390625f // tail scale 1/256 (exact)
#define TSCI 256.0f      // inverse

// ST (S^T [k][n]) and A-slab: stride 256 halves with XOR swizzle, write and
// read sides use the SAME formula (both-sides-or-neither).
#define SW_ST(k, n)  ((k) * 256 + ((n) ^ (((k) & 7) << 3)))   // half idx
#define SW_AW(r, w)  ((r) * 128 + ((w) ^ (((r) & 7) << 2)))   // word idx
#define SW_AH(r, h)  ((r) * 256 + ((h) ^ (((r) & 7) << 3)))   // half idx

// NOTE (R1): fused k1a+k2+k3 into per-graph megakernel; 321 -> 316 total.
// NOTE (R2-R5): LDS diet 127->65KB: occupancy pinned ~45% regardless --
// 1024-thr blocks run 1/CU. Optimize single-block critical path only.
// NOTE (R5/R6): irregular AS-gather REGRESSED (290us); dense slabs win.
// NOTE (R7): in-register P+softmax -> mega 199->159.
// NOTE (R8): weights staged in-block (kw_conv deleted), 2x128-row slabs ->
// mega 147, total 239.7. Non-mega gap ~93us is fixed harness overhead.
// NOTE (R9): bundled 6 changes -> mega 159 (REGRESSED +12). Suspect: 16-lane
// gather (halved node-parallelism: 4 passes x 8 serial = 2 x 16 -- no net
// chain reduction, added shfl+divergence; occupancy 44->38 tail skew).
// NOTE (R10): surgical revert of the gather to R8's 8-lane form; keep R9's
// work-reducing changes (int4 decode, zero trims, SP->WWT + xp||slab-0
// merge, fused 6-value end reduce, 20 barriers).

typedef __attribute__((ext_vector_type(8))) _Float16 v8h;
typedef __attribute__((ext_vector_type(4))) float v4f;

// ws[0]=sumA2, ws[1]=sum S logS, ws[2]=trace(Ap), ws[3]=||G||^2
__global__ void finalize_k(const float* __restrict__ ws, float* __restrict__ out) {
    if (threadIdx.x == 0) {
        float num = ws[0] - 2.f * ws[2] + ws[3];
        float link = sqrtf(fmaxf(num, 0.f)) / 67108864.0f;   // / (B*n*n)
        float ent  = -ws[1] / 262144.0f;                     // / N
        out[2048] = link + ent;
    }
}

// ---- MEGA: per-graph fused pipeline (1 block/CU; 20 barriers) ---------------
__launch_bounds__(1024, 1)
__global__ void mega(const int* __restrict__ esrc, const int* __restrict__ edst,
                     const float* __restrict__ x,
                     const float* __restrict__ W1a, const float* __restrict__ b1a,
                     const float* __restrict__ W1b, const float* __restrict__ b1b,
                     const float* __restrict__ Wp,  const float* __restrict__ bp,
                     const float* __restrict__ W2a, const float* __restrict__ b2a,
                     const float* __restrict__ W2b, const float* __restrict__ b2b,
                     const float* __restrict__ Wl,  const float* __restrict__ bl,
                     float* __restrict__ out, float* __restrict__ ws)
{
    __shared__ __align__(16) _Float16 ST[64 * 256];   // 32 KB  S^T [k][n] swz
    __shared__ __align__(16) _Float16 xagg[NP * 8];   // 4 KB   x+agg f16
    __shared__ __align__(16) _Float16 W1bT[64 * FST]; // 9.2 KB [h2][h1] xp B
    __shared__ __align__(16) _Float16 WWT[64 * FST];  // 9.2 KB [k][h1], then SP
    __shared__ __align__(16) _Float16 W2aT[64 * FST]; // 9.2 KB [d2][d]
    __shared__ __align__(16) _Float16 W2bT[64 * FST]; // 9.2 KB [j][d2]
    __shared__ float bPl[64];                         // b1b@Wp + bp (pad 0)
    __shared__ __align__(16) union {
        struct {                                      // phase 1 (15.4 KB)
            unsigned char ssi[EPG];
            float xt8[NP * 8];
            unsigned int hist[256], cur[256], roff[NP + 1];
        } k1;
        struct {                                      // phase 0 transients
            unsigned char pad[16384];                 // (clear of k1)
            _Float16 WpT_s[64 * FST];                 // Wp^T [k][h2]
            _Float16 W1bN[64 * FST];                  // W1b  [h1][h2]
        } w;
        struct {                                      // phase 2 (70.7 KB)
            _Float16 t1b[NP * FST];                   // t1 [n][j]
            _Float16 t1T[HD * TST];                   // t1^T [j][n]
        } k2;
        struct {                                      // phase 3 slab (81 KB)
            unsigned int cnt[128 * 128];              // A slab, swizzled words
            _Float16 T1T[64 * AST2];                  // AS^T [c][n128]
        } a;
        struct {                                      // phase 3 tail (27.6 KB)
            _Float16 Apf_tf[64 * FST];                // Ap, later t*s
            _Float16 xpT[64 * FST];
            _Float16 h2f[64 * FST];
        } b;
    } u;
    __shared__ float cs[64];                          // colsum(S)
    __shared__ float red[96];

    const int g = blockIdx.x, tid = threadIdx.x;
    const int lane = tid & 63, wid = tid >> 6;        // wid 0..15
    const int l15 = lane & 15, quad = lane >> 4, fko = quad * 8;
    const int mt = (wid >> 2) << 4, nt = (wid & 3) << 4;

    // ---- A: init (hist only) ----
    if (tid < 256) u.k1.hist[tid] = 0u;
    __syncthreads();

    // ---- B: decode edges (int4->regs) + hist + stage x + weights + zeros ---
    unsigned int cellr[4];
    {
        int4 sv = ((const int4*)(esrc + g * EPG))[tid];
        int4 dv = ((const int4*)(edst + g * EPG))[tid];
        int ss[4] = {sv.x & (NP-1), sv.y & (NP-1), sv.z & (NP-1), sv.w & (NP-1)};
        int dd[4] = {dv.x & (NP-1), dv.y & (NP-1), dv.z & (NP-1), dv.w & (NP-1)};
        #pragma unroll
        for (int j = 0; j < 4; ++j) {
            cellr[j] = (unsigned)((ss[j] << 8) | dd[j]);
            atomicAdd(&u.k1.hist[dd[j]], 1u);
        }
    }
    for (int i = tid; i < NP * 8; i += 1024) {
        int n = i >> 3, f = i & 7;
        u.k1.xt8[i] = (f < FIN) ? x[g * NP * FIN + n * FIN + f] : 0.f;
    }
    // weight staging (coalesced f32 reads, L2/L3-hot; f16 LDS writes)
    #pragma unroll
    for (int j = 0; j < 4; ++j) {
        int i = tid + j * 1024;                       // i < 4096
        int a0 = i >> 6, b0 = i & 63;
        W1bT[b0 * FST + a0] = (_Float16)W1b[i];       // [h2][h1]
        u.w.W1bN[a0 * FST + b0] = (_Float16)W1b[i];   // natural copy
        W2aT[b0 * FST + a0] = (_Float16)W2a[i];       // [d2][d]
        W2bT[b0 * FST + a0] = (_Float16)W2b[i];       // [j][d2]
    }
    for (int i = tid; i < HD * KC; i += 1024) {       // Wp [h2][k], k<50
        int h2 = i / KC, k = i - h2 * KC;
        u.w.WpT_s[k * FST + h2] = (_Float16)Wp[i];
    }
    // zero pads: WpT_s rows 50-63 cols 0-63; ST rows 50-63 (full)
    for (int i = tid; i < 14 * 64; i += 1024) {
        int k = 50 + (i >> 6), h2 = i & 63;
        u.w.WpT_s[k * FST + h2] = (_Float16)0.f;
    }
    for (int i = tid; i < 14 * 128; i += 1024)
        ((unsigned int*)ST)[(50 + (i >> 7)) * 128 + (i & 127)] = 0u;
    __syncthreads();

    // ---- C: scan (wave 0) || WW MFMA fold || bP fold ----
    if (wid == 0) {
        unsigned carry = 0;
        for (int c = 0; c < 4; ++c) {
            unsigned v = u.k1.hist[c * 64 + lane];
            unsigned s = v;
            #pragma unroll
            for (int o = 1; o < 64; o <<= 1) {
                unsigned t = __shfl_up(s, o);
                if (lane >= o) s += t;
            }
            unsigned excl = s - v + carry;
            u.k1.roff[c * 64 + lane] = excl;
            u.k1.cur[c * 64 + lane] = excl;
            carry += __shfl(s, 63);
        }
        if (lane == 0) u.k1.roff[NP] = EPG;
    }
    {   // WWT[k][h1] = sum_h2 Wp[h2][k] W1b[h1][h2]
        v4f acc = {0.f, 0.f, 0.f, 0.f};
        #pragma unroll
        for (int ks = 0; ks < 2; ++ks) {
            v8h af = *(const v8h*)&u.w.WpT_s[(mt + l15) * FST + ks * 32 + fko];
            v8h bf = *(const v8h*)&u.w.W1bN[(nt + l15) * FST + ks * 32 + fko];
            acc = __builtin_amdgcn_mfma_f32_16x16x32_f16(af, bf, acc, 0, 0, 0);
        }
        #pragma unroll
        for (int r = 0; r < 4; ++r)
            WWT[(mt + quad * 4 + r) * FST + nt + l15] = (_Float16)acc[r];
    }
    {   // bP[k] = sum_d b1b[d] Wp[d][k] + bp[k]  (16 lanes per k)
        int k = tid >> 4, q = tid & 15;
        float v = 0.f;
        #pragma unroll
        for (int d0 = 0; d0 < 4; ++d0) {
            int d = q * 4 + d0;
            v += b1b[d] * (float)u.w.WpT_s[k * FST + d];
        }
        #pragma unroll
        for (int o = 8; o > 0; o >>= 1) v += __shfl_xor(v, o);
        if (q == 0) bPl[k] = v + ((k < KC) ? bp[k] : 0.f);
    }
    __syncthreads();

    // ---- D: scatter ----
    #pragma unroll
    for (int j = 0; j < 4; ++j) {
        unsigned c = cellr[j];
        unsigned p2 = atomicAdd(&u.k1.cur[c & 255u], 1u);
        u.k1.ssi[p2] = (unsigned char)(c >> 8);
    }
    __syncthreads();

    // ---- E: gather agg, 8 lanes/node (R8 form; R9's 16-lane regressed) ----
    {
        const int gi = tid >> 3, f = tid & 7;
        for (int n = gi; n < NP; n += 128) {
            int beg = u.k1.roff[n], end = u.k1.roff[n + 1];
            float a = u.k1.xt8[n * 8 + f];
            for (int e = beg; e < end; ++e)
                a += u.k1.xt8[u.k1.ssi[e] * 8 + f];
            xagg[n * 8 + f] = (_Float16)a;
        }
    }
    __syncthreads();

    // ---- F: t1 = relu((x+agg) @ W1a + b1a), all 256 rows ----
    {
        float w1r[FIN];
        #pragma unroll
        for (int f = 0; f < FIN; ++f) w1r[f] = W1a[f * HD + lane];
        float b1r = b1a[lane];
        for (int it = 0; it < 16; ++it) {
            int n = it * 16 + wid;
            float a = b1r;
            #pragma unroll
            for (int f = 0; f < FIN; ++f)
                a += (float)xagg[n * 8 + f] * w1r[f];
            _Float16 tv = (_Float16)fmaxf(a, 0.f);
            u.k2.t1b[n * FST + lane] = tv;
            u.k2.t1T[lane * TST + n] = tv;
        }
    }
    __syncthreads();

    // ---- G: P + softmax in-register; each wave owns 16 rows ----
    float entL = 0.f;
    {
        const int r16 = wid << 4;
        v4f pa[4];
        #pragma unroll
        for (int c = 0; c < 4; ++c) {
            v4f acc = {0.f, 0.f, 0.f, 0.f};
            #pragma unroll
            for (int ks = 0; ks < 2; ++ks) {
                v8h af = *(const v8h*)&u.k2.t1b[(r16 + l15) * FST + ks * 32 + fko];
                v8h bf = *(const v8h*)&WWT[(c * 16 + l15) * FST + ks * 32 + fko];
                acc = __builtin_amdgcn_mfma_f32_16x16x32_f16(af, bf, acc, 0, 0, 0);
            }
            pa[c] = acc;
        }
        float bv[4]; bool valid[4];
        #pragma unroll
        for (int c = 0; c < 4; ++c) {
            int col = c * 16 + l15;
            bv[c] = bPl[col];
            valid[c] = col < KC;
        }
        #pragma unroll
        for (int r = 0; r < 4; ++r) {
            float pv[4];
            #pragma unroll
            for (int c = 0; c < 4; ++c)
                pv[c] = valid[c] ? (pa[c][r] + bv[c]) : -INFINITY;
            float m = fmaxf(fmaxf(pv[0], pv[1]), fmaxf(pv[2], pv[3]));
            #pragma unroll
            for (int o = 8; o > 0; o >>= 1) m = fmaxf(m, __shfl_xor(m, o));
            float e[4], Z = 0.f;
            #pragma unroll
            for (int c = 0; c < 4; ++c) {
                e[c] = valid[c] ? __expf(pv[c] - m) : 0.f;
                Z += e[c];
            }
            #pragma unroll
            for (int o = 8; o > 0; o >>= 1) Z += __shfl_xor(Z, o);
            float zi = 1.f / Z, lZ = __logf(Z);
            int row = r16 + quad * 4 + r;
            #pragma unroll
            for (int c = 0; c < 4; ++c) {
                if (valid[c]) {
                    float s = e[c] * zi;
                    ST[SW_ST(c * 16 + l15, row)] = (_Float16)s;
                    entL += s * (pv[c] - m);     // sum s*log s = this - logZ
                }
            }
            if (l15 == 0) entL -= lZ;
        }
    }
    __syncthreads();

    // ---- H: SP = S^T t1 (K=256); SP tile -> WWT (dead); cs ----
    {
        v4f spa = {0.f, 0.f, 0.f, 0.f};
        const int ar = mt + l15, br = nt + l15;
        #pragma unroll
        for (int ks = 0; ks < 8; ++ks) {
            int ko = ks * 32 + fko;
            v8h af = *(const v8h*)&ST[SW_ST(ar, ko)];
            v8h bf = *(const v8h*)&u.k2.t1T[br * TST + ko];
            spa = __builtin_amdgcn_mfma_f32_16x16x32_f16(af, bf, spa, 0, 0, 0);
        }
        int c = nt + l15;
        #pragma unroll
        for (int r = 0; r < 4; ++r)
            WWT[(mt + quad * 4 + r) * FST + c] = (_Float16)spa[r];
    }
    {   // colsum(S) partials -> cs
        int k = tid >> 4, q = tid & 15;
        float v = 0.f;
        #pragma unroll
        for (int i = 0; i < 16; ++i) v += (float)ST[SW_ST(k, q * 16 + i)];
        #pragma unroll
        for (int o = 8; o > 0; o >>= 1) v += __shfl_xor(v, o);
        if (q == 0) cs[k] = v;
    }
    __syncthreads();

    // ---- I: zero cnt (slab 0) ----
    for (int i = tid; i < 128 * 128; i += 1024) u.a.cnt[i] = 0u;
    __syncthreads();

    // ---- J: xp = SP @ W1b + cs (x) b1b  ||  slab-0 atomic build ----
    v4f axp;
    {
        const int d = nt + l15;
        float bv = b1b[d];
        #pragma unroll
        for (int r = 0; r < 4; ++r) axp[r] = cs[mt + quad * 4 + r] * bv;
        #pragma unroll
        for (int ks = 0; ks < 2; ++ks) {
            v8h af = *(const v8h*)&WWT[(mt + l15) * FST + ks * 32 + fko];
            v8h bf = *(const v8h*)&W1bT[(nt + l15) * FST + ks * 32 + fko];
            axp = __builtin_amdgcn_mfma_f32_16x16x32_f16(af, bf, axp, 0, 0, 0);
        }
    }
    float sumA2 = 0.f;
    v4f ap = {0.f, 0.f, 0.f, 0.f};
    v4f ag = {0.f, 0.f, 0.f, 0.f};
    float tr = 0.f, g2 = 0.f, l0 = 0.f, l1 = 0.f;

    #pragma unroll
    for (int j = 0; j < 4; ++j) {
        unsigned c = cellr[j];
        int sr = (int)(c >> 8);
        if (sr < 128) {
            int d = c & 255u;
            atomicAdd(&u.a.cnt[SW_AW(sr, d >> 1)], (d & 1) ? 0x10000u : 1u);
        }
    }
    __syncthreads();

    // ---- slabs 0,1: convert -> AS -> ApG (+zero/build next) ----
    for (int ch = 0; ch < 2; ++ch) {
        // sum(A^2) partial + in-place convert counts -> f16
        for (int i = tid; i < 128 * 128; i += 1024) {
            unsigned v = u.a.cnt[i];
            float m0 = (float)(v & 0xffffu), m1 = (float)(v >> 16);
            sumA2 += m0 * m0 + m1 * m1;
            union { unsigned uu; _Float16 h[2]; } cv;
            cv.h[0] = (_Float16)m0; cv.h[1] = (_Float16)m1;
            u.a.cnt[i] = cv.uu;
        }
        __syncthreads();

        const _Float16* Af = (const _Float16*)u.a.cnt;

        // AS_slab = A_slab @ S : [128][64] out, 32 tiles, 2 per wave
        #pragma unroll
        for (int tt = 0; tt < 2; ++tt) {
            int t = wid + tt * 16;
            int mt3 = (t >> 2) << 4, nt3 = (t & 3) << 4;
            v4f acc = {0.f, 0.f, 0.f, 0.f};
            #pragma unroll
            for (int ks = 0; ks < 8; ++ks) {
                v8h af = *(const v8h*)&Af[SW_AH(mt3 + l15, ks * 32 + fko)];
                v8h bf = *(const v8h*)&ST[SW_ST(nt3 + l15, ks * 32 + fko)];
                acc = __builtin_amdgcn_mfma_f32_16x16x32_f16(af, bf, acc, 0, 0, 0);
            }
            int c = nt3 + l15;
            #pragma unroll
            for (int r = 0; r < 4; ++r)
                u.a.T1T[c * AST2 + mt3 + quad * 4 + r] = (_Float16)acc[r];
        }
        __syncthreads();

        // Ap += S^T AS; G += S^T S (K=128)
        {
            const int ar = mt + l15, br = nt + l15;
            #pragma unroll
            for (int ks = 0; ks < 4; ++ks) {
                int ko = (ch << 7) + ks * 32 + fko;
                v8h af = *(const v8h*)&ST[SW_ST(ar, ko)];
                v8h bt = *(const v8h*)&u.a.T1T[br * AST2 + ks * 32 + fko];
                v8h bs = *(const v8h*)&ST[SW_ST(br, ko)];
                ap = __builtin_amdgcn_mfma_f32_16x16x32_f16(af, bt, ap, 0, 0, 0);
                ag = __builtin_amdgcn_mfma_f32_16x16x32_f16(af, bs, ag, 0, 0, 0);
            }
        }
        if (ch == 0) {
            for (int i = tid; i < 128 * 128; i += 1024) u.a.cnt[i] = 0u;
            __syncthreads();
            // slab-1 atomic build
            #pragma unroll
            for (int j = 0; j < 4; ++j) {
                unsigned c = cellr[j];
                int sr = (int)(c >> 8) - 128;
                if (sr >= 0) {
                    int d = c & 255u;
                    atomicAdd(&u.a.cnt[SW_AW(sr, d >> 1)],
                              (d & 1) ? 0x10000u : 1u);
                }
            }
            __syncthreads();
        } else {
            // scalars + f16 Ap / xp^T into tail buffers (cnt/T1T dead)
            int c = nt + l15;
            #pragma unroll
            for (int r = 0; r < 4; ++r) {
                int k = mt + quad * 4 + r;
                u.b.Apf_tf[k * FST + c] = (_Float16)ap[r];
                u.b.xpT[c * FST + k] = (_Float16)axp[r];
                if (k < KC && c < KC) {
                    if (k == c) tr += ap[r];
                    g2 += ag[r] * ag[r];
                }
            }
            __syncthreads();
        }
    }

    // ---- R: h2 = xp + Ap @ xp, scaled by 1/256 ----
    {
        v4f hacc = axp;
        #pragma unroll
        for (int ks = 0; ks < 2; ++ks) {
            v8h af = *(const v8h*)&u.b.Apf_tf[(mt + l15) * FST + ks * 32 + fko];
            v8h bf = *(const v8h*)&u.b.xpT[(nt + l15) * FST + ks * 32 + fko];
            hacc = __builtin_amdgcn_mfma_f32_16x16x32_f16(af, bf, hacc, 0, 0, 0);
        }
        int d = nt + l15;
        #pragma unroll
        for (int r = 0; r < 4; ++r)
            u.b.h2f[(mt + quad * 4 + r) * FST + d] = (_Float16)(hacc[r] * TSC);
    }
    __syncthreads();

    // ---- S: t*s = relu(h2s @ W2a + s*b2a) -> overwrites Apf ----
    {
        float bv = b2a[nt + l15] * TSC;
        v4f tacc = {bv, bv, bv, bv};
        #pragma unroll
        for (int ks = 0; ks < 2; ++ks) {
            v8h af = *(const v8h*)&u.b.h2f[(mt + l15) * FST + ks * 32 + fko];
            v8h bf = *(const v8h*)&W2aT[(nt + l15) * FST + ks * 32 + fko];
            tacc = __builtin_amdgcn_mfma_f32_16x16x32_f16(af, bf, tacc, 0, 0, 0);
        }
        int d2 = nt + l15;
        #pragma unroll
        for (int r = 0; r < 4; ++r)
            u.b.Apf_tf[(mt + quad * 4 + r) * FST + d2] = (_Float16)fmaxf(tacc[r], 0.f);
    }
    __syncthreads();

    // ---- T: h3 = (t*s)@W2b * 256 + b2b; fold mean + Wl in fp32 ----
    {
        v4f oacc = {0.f, 0.f, 0.f, 0.f};
        #pragma unroll
        for (int ks = 0; ks < 2; ++ks) {
            v8h af = *(const v8h*)&u.b.Apf_tf[(mt + l15) * FST + ks * 32 + fko];
            v8h bf = *(const v8h*)&W2bT[(nt + l15) * FST + ks * 32 + fko];
            oacc = __builtin_amdgcn_mfma_f32_16x16x32_f16(af, bf, oacc, 0, 0, 0);
        }
        int j = nt + l15;
        float bv = b2b[j];
        float wl0 = Wl[j * 2], wl1 = Wl[j * 2 + 1];
        #pragma unroll
        for (int r = 0; r < 4; ++r) {
            int k = mt + quad * 4 + r;
            if (k < KC) {
                float h3v = oacc[r] * TSCI + bv;
                l0 += h3v * wl0; l1 += h3v * wl1;
            }
        }
    }

    // ---- U: single fused 6-value reduce (no leading barrier: regs only) ----
    #pragma unroll
    for (int o = 32; o > 0; o >>= 1) {
        sumA2 += __shfl_down(sumA2, o);
        entL  += __shfl_down(entL,  o);
        tr    += __shfl_down(tr,    o);
        g2    += __shfl_down(g2,    o);
        l0    += __shfl_down(l0,    o);
        l1    += __shfl_down(l1,    o);
    }
    if (lane == 0) {
        red[wid * 6 + 0] = sumA2; red[wid * 6 + 1] = entL;
        red[wid * 6 + 2] = tr;    red[wid * 6 + 3] = g2;
        red[wid * 6 + 4] = l0;    red[wid * 6 + 5] = l1;
    }
    __syncthreads();
    if (tid == 0) {
        float s0 = 0.f, s1 = 0.f, s2 = 0.f, s3 = 0.f, s4 = 0.f, s5 = 0.f;
        for (int i = 0; i < 16; ++i) {
            s0 += red[i * 6];     s1 += red[i * 6 + 1];
            s2 += red[i * 6 + 2]; s3 += red[i * 6 + 3];
            s4 += red[i * 6 + 4]; s5 += red[i * 6 + 5];
        }
        atomicAdd(&ws[0], s0);
        atomicAdd(&ws[1], s1);
        atomicAdd(&ws[2], s2);
        atomicAdd(&ws[3], s3);
        float g0 = bl[0] + s4 * (1.f / KC);
        float g1 = bl[1] + s5 * (1.f / KC);
        float mm = fmaxf(g0, g1);
        float lse = mm + __logf(__expf(g0 - mm) + __expf(g1 - mm));
        out[2 * g]     = g0 - lse;
        out[2 * g + 1] = g1 - lse;
    }
}

extern "C" void kernel_launch(void* const* d_in, const int* in_sizes, int n_in,
                              void* d_out, int out_size, void* d_ws, size_t ws_size,
                              hipStream_t stream) {
    const float* x    = (const float*)d_in[0];
    const float* W1a  = (const float*)d_in[1];
    const float* b1a  = (const float*)d_in[2];
    const float* W1b  = (const float*)d_in[3];
    const float* b1b  = (const float*)d_in[4];
    const float* Wp   = (const float*)d_in[5];
    const float* bp   = (const float*)d_in[6];
    const float* W2a  = (const float*)d_in[7];
    const float* b2a  = (const float*)d_in[8];
    const float* W2b  = (const float*)d_in[9];
    const float* b2b  = (const float*)d_in[10];
    const float* Wl   = (const float*)d_in[11];
    const float* bl   = (const float*)d_in[12];
    const int*   eidx = (const int*)d_in[13];   // [2, E] int32
    float* out = (float*)d_out;
    float* ws  = (float*)d_ws;

    hipMemsetAsync(ws, 0, 4 * sizeof(float), stream);
    mega<<<NG, 1024, 0, stream>>>(eidx, eidx + ETOT, x,
                                  W1a, b1a, W1b, b1b, Wp, bp,
                                  W2a, b2a, W2b, b2b, Wl, bl, out, ws);
    finalize_k<<<1, 64, 0, stream>>>(ws, out);
}

// Round 11
// 234.592 us; speedup vs baseline: 1.0532x; 1.0532x over previous
//
#include <hip/hip_runtime.h>
#include <math.h>

// Problem constants (from reference)
#define NG   1024        // graphs
#define NP   256         // nodes per graph
#define EPG  4096        // edges per graph
#define ETOT 4194304     // total edges
#define FIN  7
#define HD   64
#define KC   50
#define FST  72          // f16 LDS row stride for 64-col tiles (36w = 4 mod 32)
#define TST  264         // t1T row stride halves (132w = 4 mod 32)
#define AST2 132         // T1T row stride halves (66w = 2 mod 32)
#define TSC  0.00390625f // tail scale 1/256 (exact)
#define TSCI 256.0f      // inverse

// ST (S^T [k][n]) and A-slab: stride 256 halves with XOR swizzle, write and
// read sides use the SAME formula (both-sides-or-neither).
#define SW_ST(k, n)  ((k) * 256 + ((n) ^ (((k) & 7) << 3)))   // half idx
#define SW_AW(r, w)  ((r) * 128 + ((w) ^ (((r) & 7) << 2)))   // word idx
#define SW_AH(r, h)  ((r) * 256 + ((h) ^ (((r) & 7) << 3)))   // half idx

// NOTE (R1): fused k1a+k2+k3 into per-graph megakernel; 321 -> 316 total.
// NOTE (R2-R5): LDS diet 127->65KB: occupancy pinned ~45% regardless --
// 1024-thr blocks run 1/CU. Optimize single-block critical path only.
// NOTE (R5/R6): irregular AS-gather REGRESSED (290us); dense slabs win.
// NOTE (R7): in-register P+softmax -> mega 199->159.
// NOTE (R8): weights staged in-block (kw_conv deleted), 2x128-row slabs ->
// mega 147, total 239.7 (SESSION BEST). Non-mega ~93us = fixed overhead.
// NOTE (R9): bundled 6 changes -> mega 159, occ 44->38 (REGRESSED +12).
// NOTE (R10): gather revert did NOT recover (157, occ 38): regressor is in
// {int4 decode, zero-trim placement, SP->WWT+merged-J, fused end reduce}.
// Busy time identical R8 vs R10 (VALU ~52us, MFMA ~8us) -> the +10us is
// pure stall from codegen/scheduling perturbation; not localizable from
// whole-kernel counters. THIS ROUND: exact R8 restore (bit-for-bit).
// Future experiments: one change at a time from this base.

typedef __attribute__((ext_vector_type(8))) _Float16 v8h;
typedef __attribute__((ext_vector_type(4))) float v4f;

// ws[0]=sumA2, ws[1]=sum S logS, ws[2]=trace(Ap), ws[3]=||G||^2
__global__ void finalize_k(const float* __restrict__ ws, float* __restrict__ out) {
    if (threadIdx.x == 0) {
        float num = ws[0] - 2.f * ws[2] + ws[3];
        float link = sqrtf(fmaxf(num, 0.f)) / 67108864.0f;   // / (B*n*n)
        float ent  = -ws[1] / 262144.0f;                     // / N
        out[2048] = link + ent;
    }
}

__device__ __forceinline__ float blockReduceN(float v, float* red, int nw) {
    __syncthreads();
    #pragma unroll
    for (int o = 32; o > 0; o >>= 1) v += __shfl_down(v, o);
    if ((threadIdx.x & 63) == 0) red[threadIdx.x >> 6] = v;
    __syncthreads();
    float r = 0.f;
    if (threadIdx.x == 0) {
        for (int i = 0; i < nw; ++i) r += red[i];
    }
    return r;
}

// 3-value fused block reduce: one barrier pair instead of three.
__device__ __forceinline__ void blockReduce3(float& a, float& b, float& c,
                                             float* red) {
    __syncthreads();
    #pragma unroll
    for (int o = 32; o > 0; o >>= 1) {
        a += __shfl_down(a, o);
        b += __shfl_down(b, o);
        c += __shfl_down(c, o);
    }
    const int wid = threadIdx.x >> 6;
    if ((threadIdx.x & 63) == 0) {
        red[wid * 3] = a; red[wid * 3 + 1] = b; red[wid * 3 + 2] = c;
    }
    __syncthreads();
    if (threadIdx.x == 0) {
        float ra = 0.f, rb = 0.f, rc = 0.f;
        for (int i = 0; i < 16; ++i) {
            ra += red[i * 3]; rb += red[i * 3 + 1]; rc += red[i * 3 + 2];
        }
        a = ra; b = rb; c = rc;
    }
}

// ---- MEGA: per-graph fused pipeline (1 block/CU; minimize barriers) ---------
// Phase 0: weight staging f32->f16 LDS + WW=W1b@Wp MFMA fold + bP fold
//          (overlapped with phase 1 histogram/scan)
// Phase 1: edge decode + di counting sort + gather GIN agg  -> xagg (f16)
// Phase 2: t1 (all 256 rows) -> P+softmax in-register       -> ST
//          SP = S^T t1 (K=256) -> xp = SP@W1b + cs (x) b1b  -> axp (regs)
// Phase 3: 2 x 128-row dense-A slabs + AS/Ap/G MFMA + head  -> out
__launch_bounds__(1024, 1)
__global__ void mega(const int* __restrict__ esrc, const int* __restrict__ edst,
                     const float* __restrict__ x,
                     const float* __restrict__ W1a, const float* __restrict__ b1a,
                     const float* __restrict__ W1b, const float* __restrict__ b1b,
                     const float* __restrict__ Wp,  const float* __restrict__ bp,
                     const float* __restrict__ W2a, const float* __restrict__ b2a,
                     const float* __restrict__ W2b, const float* __restrict__ b2b,
                     const float* __restrict__ Wl,  const float* __restrict__ bl,
                     float* __restrict__ out, float* __restrict__ ws)
{
    __shared__ __align__(16) _Float16 ST[64 * 256];   // 32 KB  S^T [k][n] swz
    __shared__ __align__(16) _Float16 xagg[NP * 8];   // 4 KB   x+agg f16
    __shared__ __align__(16) _Float16 W1bT[64 * FST]; // 9.2 KB [h2][h1] xp B
    __shared__ __align__(16) _Float16 WWT[64 * FST];  // 9.2 KB [k][h1], then SP
    __shared__ __align__(16) _Float16 W2aT[64 * FST]; // 9.2 KB [d2][d]
    __shared__ __align__(16) _Float16 W2bT[64 * FST]; // 9.2 KB [j][d2]
    __shared__ float bPl[64];                         // b1b@Wp + bp (pad 0)
    __shared__ __align__(16) union {
        struct {                                      // phase 1 (15.4 KB)
            unsigned char ssi[EPG];
            float xt8[NP * 8];
            unsigned int hist[256], cur[256], roff[NP + 1];
        } k1;
        struct {                                      // phase 0 transients
            unsigned char pad[16384];                 // (clear of k1)
            _Float16 WpT_s[64 * FST];                 // Wp^T [k][h2]
            _Float16 W1bN[64 * FST];                  // W1b  [h1][h2]
        } w;
        struct {                                      // phase 2 (70.7 KB)
            _Float16 t1b[NP * FST];                   // t1 [n][j]
            _Float16 t1T[HD * TST];                   // t1^T [j][n]
        } k2;
        struct {                                      // phase 3 slab (81 KB)
            unsigned int cnt[128 * 128];              // A slab, swizzled words
            _Float16 T1T[64 * AST2];                  // AS^T [c][n128]
        } a;
        struct {                                      // phase 3 tail (27.6 KB)
            _Float16 Apf_tf[64 * FST];                // Ap, later t*s
            _Float16 xpT[64 * FST];
            _Float16 h2f[64 * FST];
        } b;
    } u;
    __shared__ float cs[64];                          // colsum(S)
    __shared__ float red[48];

    const int g = blockIdx.x, tid = threadIdx.x;
    const int lane = tid & 63, wid = tid >> 6;        // wid 0..15
    const int l15 = lane & 15, quad = lane >> 4, fko = quad * 8;
    const int mt = (wid >> 2) << 4, nt = (wid & 3) << 4;

    // ---- init: zero ST (rows k>=50 must stay 0), WpT_s, histograms ----
    for (int i = tid; i < 64 * 128; i += 1024) ((unsigned int*)ST)[i] = 0u;
    for (int i = tid; i < 64 * FST / 2; i += 1024) ((unsigned int*)u.w.WpT_s)[i] = 0u;
    if (tid < 256) u.k1.hist[tid] = 0u;
    __syncthreads();

    // ---- phase 1a: decode edges (regs) + histogram + stage x + weights ----
    unsigned int cellr[4];
    #pragma unroll
    for (int j = 0; j < 4; ++j) {
        int e = tid + j * 1024;
        int s = esrc[g * EPG + e] & (NP - 1);
        int d = edst[g * EPG + e] & (NP - 1);
        cellr[j] = (unsigned)((s << 8) | d);
        atomicAdd(&u.k1.hist[d], 1u);
    }
    for (int i = tid; i < NP * 8; i += 1024) {
        int n = i >> 3, f = i & 7;
        u.k1.xt8[i] = (f < FIN) ? x[g * NP * FIN + n * FIN + f] : 0.f;
    }
    // weight staging (coalesced f32 reads, L2/L3-hot; f16 LDS writes)
    #pragma unroll
    for (int j = 0; j < 4; ++j) {
        int i = tid + j * 1024;                       // i < 4096
        int a0 = i >> 6, b0 = i & 63;
        W1bT[b0 * FST + a0] = (_Float16)W1b[i];       // [h2][h1]
        u.w.W1bN[a0 * FST + b0] = (_Float16)W1b[i];   // natural copy
        W2aT[b0 * FST + a0] = (_Float16)W2a[i];       // [d2][d]
        W2bT[b0 * FST + a0] = (_Float16)W2b[i];       // [j][d2]
    }
    for (int i = tid; i < HD * KC; i += 1024) {       // Wp [h2][k], k<50
        int h2 = i / KC, k = i - h2 * KC;
        u.w.WpT_s[k * FST + h2] = (_Float16)Wp[i];    // rows k>=50 stay 0
    }
    __syncthreads();

    // ---- phase 1b: scan (wave 0) || WW MFMA fold || bP fold ----
    if (wid == 0) {
        unsigned carry = 0;
        for (int c = 0; c < 4; ++c) {
            unsigned v = u.k1.hist[c * 64 + lane];
            unsigned s = v;
            #pragma unroll
            for (int o = 1; o < 64; o <<= 1) {
                unsigned t = __shfl_up(s, o);
                if (lane >= o) s += t;
            }
            unsigned excl = s - v + carry;
            u.k1.roff[c * 64 + lane] = excl;
            u.k1.cur[c * 64 + lane] = excl;
            carry += __shfl(s, 63);
        }
        if (lane == 0) u.k1.roff[NP] = EPG;
    }
    {   // WWT[k][h1] = sum_h2 Wp[h2][k] W1b[h1][h2]
        v4f acc = {0.f, 0.f, 0.f, 0.f};
        #pragma unroll
        for (int ks = 0; ks < 2; ++ks) {
            v8h af = *(const v8h*)&u.w.WpT_s[(mt + l15) * FST + ks * 32 + fko];
            v8h bf = *(const v8h*)&u.w.W1bN[(nt + l15) * FST + ks * 32 + fko];
            acc = __builtin_amdgcn_mfma_f32_16x16x32_f16(af, bf, acc, 0, 0, 0);
        }
        #pragma unroll
        for (int r = 0; r < 4; ++r)
            WWT[(mt + quad * 4 + r) * FST + nt + l15] = (_Float16)acc[r];
    }
    {   // bP[k] = sum_d b1b[d] Wp[d][k] + bp[k]  (16 lanes per k)
        int k = tid >> 4, q = tid & 15;
        float v = 0.f;
        #pragma unroll
        for (int d0 = 0; d0 < 4; ++d0) {
            int d = q * 4 + d0;
            v += b1b[d] * (float)u.w.WpT_s[k * FST + d];
        }
        #pragma unroll
        for (int o = 8; o > 0; o >>= 1) v += __shfl_xor(v, o);
        if (q == 0) bPl[k] = v + ((k < KC) ? bp[k] : 0.f);
    }
    __syncthreads();

    // ---- phase 1c: scatter ----
    #pragma unroll
    for (int j = 0; j < 4; ++j) {
        unsigned c = cellr[j];
        unsigned p2 = atomicAdd(&u.k1.cur[c & 255u], 1u);
        u.k1.ssi[p2] = (unsigned char)(c >> 8);
    }
    __syncthreads();

    // ---- gather agg: 8 lanes per node -> xagg (f16) ----
    {
        const int gi = tid >> 3, f = tid & 7;
        for (int n = gi; n < NP; n += 128) {
            int beg = u.k1.roff[n], end = u.k1.roff[n + 1];
            float a = u.k1.xt8[n * 8 + f];
            for (int e = beg; e < end; ++e)
                a += u.k1.xt8[u.k1.ssi[e] * 8 + f];
            xagg[n * 8 + f] = (_Float16)a;
        }
    }
    __syncthreads();

    // ---- phase 2a: t1 = relu((x+agg) @ W1a + b1a), all 256 rows ----
    {
        float w1r[FIN];
        #pragma unroll
        for (int f = 0; f < FIN; ++f) w1r[f] = W1a[f * HD + lane];
        float b1r = b1a[lane];
        for (int it = 0; it < 16; ++it) {
            int n = it * 16 + wid;
            float a = b1r;
            #pragma unroll
            for (int f = 0; f < FIN; ++f)
                a += (float)xagg[n * 8 + f] * w1r[f];
            _Float16 tv = (_Float16)fmaxf(a, 0.f);
            u.k2.t1b[n * FST + lane] = tv;
            u.k2.t1T[lane * TST + n] = tv;
        }
    }
    __syncthreads();

    // ---- phase 2b: P + softmax in-register; each wave owns 16 rows ----
    float entL = 0.f;
    {
        const int r16 = wid << 4;
        v4f pa[4];
        #pragma unroll
        for (int c = 0; c < 4; ++c) {
            v4f acc = {0.f, 0.f, 0.f, 0.f};
            #pragma unroll
            for (int ks = 0; ks < 2; ++ks) {
                v8h af = *(const v8h*)&u.k2.t1b[(r16 + l15) * FST + ks * 32 + fko];
                v8h bf = *(const v8h*)&WWT[(c * 16 + l15) * FST + ks * 32 + fko];
                acc = __builtin_amdgcn_mfma_f32_16x16x32_f16(af, bf, acc, 0, 0, 0);
            }
            pa[c] = acc;
        }
        float bv[4]; bool valid[4];
        #pragma unroll
        for (int c = 0; c < 4; ++c) {
            int col = c * 16 + l15;
            bv[c] = bPl[col];
            valid[c] = col < KC;
        }
        #pragma unroll
        for (int r = 0; r < 4; ++r) {
            float pv[4];
            #pragma unroll
            for (int c = 0; c < 4; ++c)
                pv[c] = valid[c] ? (pa[c][r] + bv[c]) : -INFINITY;
            float m = fmaxf(fmaxf(pv[0], pv[1]), fmaxf(pv[2], pv[3]));
            #pragma unroll
            for (int o = 8; o > 0; o >>= 1) m = fmaxf(m, __shfl_xor(m, o));
            float e[4], Z = 0.f;
            #pragma unroll
            for (int c = 0; c < 4; ++c) {
                e[c] = valid[c] ? __expf(pv[c] - m) : 0.f;
                Z += e[c];
            }
            #pragma unroll
            for (int o = 8; o > 0; o >>= 1) Z += __shfl_xor(Z, o);
            float zi = 1.f / Z, lZ = __logf(Z);
            int row = r16 + quad * 4 + r;
            #pragma unroll
            for (int c = 0; c < 4; ++c) {
                if (valid[c]) {
                    float s = e[c] * zi;
                    ST[SW_ST(c * 16 + l15, row)] = (_Float16)s;
                    entL += s * (pv[c] - m);     // sum s*log s = this - logZ
                }
            }
            if (l15 == 0) entL -= lZ;
        }
    }
    __syncthreads();

    // ---- phase 2c: SP = S^T t1 (K=256); SP tile -> SPb (t1b); cs ----
    {
        v4f spa = {0.f, 0.f, 0.f, 0.f};
        const int ar = mt + l15, br = nt + l15;
        #pragma unroll
        for (int ks = 0; ks < 8; ++ks) {
            int ko = ks * 32 + fko;
            v8h af = *(const v8h*)&ST[SW_ST(ar, ko)];
            v8h bf = *(const v8h*)&u.k2.t1T[br * TST + ko];
            spa = __builtin_amdgcn_mfma_f32_16x16x32_f16(af, bf, spa, 0, 0, 0);
        }
        _Float16* SPb = u.k2.t1b;
        int c = nt + l15;
        #pragma unroll
        for (int r = 0; r < 4; ++r)
            SPb[(mt + quad * 4 + r) * FST + c] = (_Float16)spa[r];
    }
    {   // colsum(S) partials -> cs
        int k = tid >> 4, q = tid & 15;
        float v = 0.f;
        #pragma unroll
        for (int i = 0; i < 16; ++i) v += (float)ST[SW_ST(k, q * 16 + i)];
        #pragma unroll
        for (int o = 8; o > 0; o >>= 1) v += __shfl_xor(v, o);
        if (q == 0) cs[k] = v;
    }
    {
        float rE = blockReduceN(entL, red, 16);   // syncs fence SPb/cs writes
        if (tid == 0) atomicAdd(&ws[1], rE);
    }

    // xp = SP @ W1b + cs (x) b1b   (tile kept in regs through phase 3)
    v4f axp;
    {
        const int d = nt + l15;
        float bv = b1b[d];
        #pragma unroll
        for (int r = 0; r < 4; ++r) axp[r] = cs[mt + quad * 4 + r] * bv;
        #pragma unroll
        for (int ks = 0; ks < 2; ++ks) {
            v8h af = *(const v8h*)&u.k2.t1b[(mt + l15) * FST + ks * 32 + fko];
            v8h bf = *(const v8h*)&W1bT[(nt + l15) * FST + ks * 32 + fko];
            axp = __builtin_amdgcn_mfma_f32_16x16x32_f16(af, bf, axp, 0, 0, 0);
        }
    }
    __syncthreads();    // SPb (aliases cnt) fully read before phase 3 zeroes

    // ---- phase 3: 2 x 128-row dense-A slabs + MFMA AS/Ap/G ----
    float sumA2 = 0.f;
    v4f ap = {0.f, 0.f, 0.f, 0.f};
    v4f ag = {0.f, 0.f, 0.f, 0.f};

    for (int i = tid; i < 128 * 128; i += 1024) u.a.cnt[i] = 0u;  // slab 0
    __syncthreads();

    for (int ch = 0; ch < 2; ++ch) {
        int rlo = ch << 7;
        #pragma unroll
        for (int j = 0; j < 4; ++j) {
            unsigned c = cellr[j];
            int sr = (int)(c >> 8) - rlo;
            if ((unsigned)sr < 128u) {
                int d = c & 255u;
                atomicAdd(&u.a.cnt[SW_AW(sr, d >> 1)],
                          (d & 1) ? 0x10000u : 1u);
            }
        }
        __syncthreads();

        // sum(A^2) partial + in-place convert counts -> f16
        for (int i = tid; i < 128 * 128; i += 1024) {
            unsigned v = u.a.cnt[i];
            float m0 = (float)(v & 0xffffu), m1 = (float)(v >> 16);
            sumA2 += m0 * m0 + m1 * m1;
            union { unsigned uu; _Float16 h[2]; } cv;
            cv.h[0] = (_Float16)m0; cv.h[1] = (_Float16)m1;
            u.a.cnt[i] = cv.uu;
        }
        __syncthreads();

        const _Float16* Af = (const _Float16*)u.a.cnt;

        // AS_slab = A_slab @ S : [128][64] out, 32 tiles, 2 per wave
        #pragma unroll
        for (int tt = 0; tt < 2; ++tt) {
            int t = wid + tt * 16;
            int mt3 = (t >> 2) << 4, nt3 = (t & 3) << 4;
            v4f acc = {0.f, 0.f, 0.f, 0.f};
            #pragma unroll
            for (int ks = 0; ks < 8; ++ks) {
                v8h af = *(const v8h*)&Af[SW_AH(mt3 + l15, ks * 32 + fko)];
                v8h bf = *(const v8h*)&ST[SW_ST(nt3 + l15, ks * 32 + fko)];
                acc = __builtin_amdgcn_mfma_f32_16x16x32_f16(af, bf, acc, 0, 0, 0);
            }
            int c = nt3 + l15;
            #pragma unroll
            for (int r = 0; r < 4; ++r)
                u.a.T1T[c * AST2 + mt3 + quad * 4 + r] = (_Float16)acc[r];
        }
        __syncthreads();

        // Ap += S^T AS; G += S^T S (K=128); zero cnt for next
        {
            const int ar = mt + l15, br = nt + l15;
            #pragma unroll
            for (int ks = 0; ks < 4; ++ks) {
                int ko = (ch << 7) + ks * 32 + fko;
                v8h af = *(const v8h*)&ST[SW_ST(ar, ko)];
                v8h bt = *(const v8h*)&u.a.T1T[br * AST2 + ks * 32 + fko];
                v8h bs = *(const v8h*)&ST[SW_ST(br, ko)];
                ap = __builtin_amdgcn_mfma_f32_16x16x32_f16(af, bt, ap, 0, 0, 0);
                ag = __builtin_amdgcn_mfma_f32_16x16x32_f16(af, bs, ag, 0, 0, 0);
            }
        }
        if (ch == 0) {
            for (int i = tid; i < 128 * 128; i += 1024) u.a.cnt[i] = 0u;
        }
        __syncthreads();
    }

    // scalars + f16 Ap / xp^T into tail buffers
    float tr = 0.f, g2 = 0.f;
    {
        int c = nt + l15;
        #pragma unroll
        for (int r = 0; r < 4; ++r) {
            int k = mt + quad * 4 + r;
            u.b.Apf_tf[k * FST + c] = (_Float16)ap[r];
            u.b.xpT[c * FST + k] = (_Float16)axp[r];
            if (k < KC && c < KC) {
                if (k == c) tr += ap[r];
                g2 += ag[r] * ag[r];
            }
        }
    }

    blockReduce3(sumA2, tr, g2, red);          // barriers fence u.b writes
    if (tid == 0) {
        atomicAdd(&ws[0], sumA2);
        atomicAdd(&ws[2], tr);
        atomicAdd(&ws[3], g2);
    }
    __syncthreads();

    // ---- MFMA tail: h2 = xp + Ap @ xp, scaled by 1/256 ----
    {
        v4f hacc = axp;
        #pragma unroll
        for (int ks = 0; ks < 2; ++ks) {
            v8h af = *(const v8h*)&u.b.Apf_tf[(mt + l15) * FST + ks * 32 + fko];
            v8h bf = *(const v8h*)&u.b.xpT[(nt + l15) * FST + ks * 32 + fko];
            hacc = __builtin_amdgcn_mfma_f32_16x16x32_f16(af, bf, hacc, 0, 0, 0);
        }
        int d = nt + l15;
        #pragma unroll
        for (int r = 0; r < 4; ++r)
            u.b.h2f[(mt + quad * 4 + r) * FST + d] = (_Float16)(hacc[r] * TSC);
    }
    __syncthreads();

    // ---- t*s = relu(h2s @ W2a + s*b2a) -> overwrites Apf ----
    {
        float bv = b2a[nt + l15] * TSC;
        v4f tacc = {bv, bv, bv, bv};
        #pragma unroll
        for (int ks = 0; ks < 2; ++ks) {
            v8h af = *(const v8h*)&u.b.h2f[(mt + l15) * FST + ks * 32 + fko];
            v8h bf = *(const v8h*)&W2aT[(nt + l15) * FST + ks * 32 + fko];
            tacc = __builtin_amdgcn_mfma_f32_16x16x32_f16(af, bf, tacc, 0, 0, 0);
        }
        int d2 = nt + l15;
        #pragma unroll
        for (int r = 0; r < 4; ++r)
            u.b.Apf_tf[(mt + quad * 4 + r) * FST + d2] = (_Float16)fmaxf(tacc[r], 0.f);
    }
    __syncthreads();

    // ---- h3 = (t*s)@W2b * 256 + b2b; fold mean + Wl in fp32 ----
    float l0 = 0.f, l1 = 0.f;
    {
        v4f oacc = {0.f, 0.f, 0.f, 0.f};
        #pragma unroll
        for (int ks = 0; ks < 2; ++ks) {
            v8h af = *(const v8h*)&u.b.Apf_tf[(mt + l15) * FST + ks * 32 + fko];
            v8h bf = *(const v8h*)&W2bT[(nt + l15) * FST + ks * 32 + fko];
            oacc = __builtin_amdgcn_mfma_f32_16x16x32_f16(af, bf, oacc, 0, 0, 0);
        }
        int j = nt + l15;
        float bv = b2b[j];
        float wl0 = Wl[j * 2], wl1 = Wl[j * 2 + 1];
        #pragma unroll
        for (int r = 0; r < 4; ++r) {
            int k = mt + quad * 4 + r;
            if (k < KC) {
                float h3v = oacc[r] * TSCI + bv;
                l0 += h3v * wl0; l1 += h3v * wl1;
            }
        }
    }

    float dummy = 0.f;
    blockReduce3(l0, l1, dummy, red);
    if (tid == 0) {
        float g0 = bl[0] + l0 * (1.f / KC);
        float g1 = bl[1] + l1 * (1.f / KC);
        float mm = fmaxf(g0, g1);
        float lse = mm + __logf(__expf(g0 - mm) + __expf(g1 - mm));
        out[2 * g]     = g0 - lse;
        out[2 * g + 1] = g1 - lse;
    }
}

extern "C" void kernel_launch(void* const* d_in, const int* in_sizes, int n_in,
                              void* d_out, int out_size, void* d_ws, size_t ws_size,
                              hipStream_t stream) {
    const float* x    = (const float*)d_in[0];
    const float* W1a  = (const float*)d_in[1];
    const float* b1a  = (const float*)d_in[2];
    const float* W1b  = (const float*)d_in[3];
    const float* b1b  = (const float*)d_in[4];
    const float* Wp   = (const float*)d_in[5];
    const float* bp   = (const float*)d_in[6];
    const float* W2a  = (const float*)d_in[7];
    const float* b2a  = (const float*)d_in[8];
    const float* W2b  = (const float*)d_in[9];
    const float* b2b  = (const float*)d_in[10];
    const float* Wl   = (const float*)d_in[11];
    const float* bl   = (const float*)d_in[12];
    const int*   eidx = (const int*)d_in[13];   // [2, E] int32
    float* out = (float*)d_out;
    float* ws  = (float*)d_ws;

    hipMemsetAsync(ws, 0, 4 * sizeof(float), stream);
    mega<<<NG, 1024, 0, stream>>>(eidx, eidx + ETOT, x,
                                  W1a, b1a, W1b, b1b, Wp, bp,
                                  W2a, b2a, W2b, b2b, Wl, bl, out, ws);
    finalize_k<<<1, 64, 0, stream>>>(ws, out);
}